// Round 3
// baseline (615.553 us; speedup 1.0000x reference)
//
#include <hip/hip_runtime.h>
#include <hip/hip_bf16.h>
#include <cstdint>

typedef __attribute__((ext_vector_type(8))) __bf16 bf16v8;
typedef __attribute__((ext_vector_type(4))) float f32x4;
typedef __attribute__((ext_vector_type(4))) unsigned short ushort4v;
typedef __attribute__((ext_vector_type(8))) unsigned short ushort8v;

#define BB 8
#define NN 2048
#define DD 768

__device__ __forceinline__ float b2f(unsigned short u) {
  union { unsigned int i; float f; } c; c.i = ((unsigned int)u) << 16; return c.f;
}
__device__ __forceinline__ unsigned short f2b(float f) {
  union { float f; unsigned int i; } c; c.f = f;
  unsigned int u = c.i;
  return (unsigned short)((u + 0x7fffu + ((u >> 16) & 1u)) >> 16);
}

// ---------------- LayerNorm: f32 [16384][768] -> bf16 ----------------
__global__ __launch_bounds__(256) void ln_kernel(const float* __restrict__ x,
                                                 const float* __restrict__ gamma,
                                                 const float* __restrict__ beta,
                                                 unsigned short* __restrict__ xb) {
  int row = blockIdx.x;
  const float* xr = x + (size_t)row * DD;
  int t = threadIdx.x;
  float a0 = xr[t], a1 = xr[t + 256], a2 = xr[t + 512];
  float s = a0 + a1 + a2;
  float q = a0 * a0 + a1 * a1 + a2 * a2;
  for (int o = 32; o > 0; o >>= 1) { s += __shfl_xor(s, o); q += __shfl_xor(q, o); }
  __shared__ float red[2][4];
  int w = t >> 6, lane = t & 63;
  if (lane == 0) { red[0][w] = s; red[1][w] = q; }
  __syncthreads();
  s = red[0][0] + red[0][1] + red[0][2] + red[0][3];
  q = red[1][0] + red[1][1] + red[1][2] + red[1][3];
  float mean = s * (1.0f / DD);
  float var = q * (1.0f / DD) - mean * mean;
  float inv = rsqrtf(var + 1e-5f);
  unsigned short* o0 = xb + (size_t)row * DD;
  o0[t]       = f2b((a0 - mean) * inv * gamma[t]       + beta[t]);
  o0[t + 256] = f2b((a1 - mean) * inv * gamma[t + 256] + beta[t + 256]);
  o0[t + 512] = f2b((a2 - mean) * inv * gamma[t + 512] + beta[t + 512]);
}

// ------------- Weight concat/convert: Wcat[2304][768] bf16, scale folded into Wq -------------
__global__ __launch_bounds__(256) void wconvert(const float* __restrict__ Wq,
                                                const float* __restrict__ Wk,
                                                const float* __restrict__ Wv,
                                                unsigned short* __restrict__ Wcat) {
  int i = blockIdx.x * 256 + threadIdx.x;
  const int dd = DD * DD;
  if (i >= 3 * dd) return;
  float v;
  if (i < dd)           v = Wq[i] * 0.03608439182435161f;   // 1/sqrt(768)
  else if (i < 2 * dd)  v = Wk[i - dd];
  else                  v = Wv[i - 2 * dd];
  Wcat[i] = f2b(v);
}

// ---------------- async global->LDS (16B per lane, wave-uniform LDS base) ----------------
__device__ __forceinline__ void gload_lds16(const void* g, void* l) {
  __builtin_amdgcn_global_load_lds(
      (const __attribute__((address_space(1))) void*)g,
      (__attribute__((address_space(3))) void*)(unsigned)(uintptr_t)l,
      16, 0, 0);
}

// 4 A-frags (rows i0..i0+3) from swizzled LDS
#define RD_A(dst, i0, ck, base)                                                          \
  _Pragma("unroll")                                                                      \
  for (int i_ = 0; i_ < 4; ++i_)                                                         \
    dst[i_] = *(const bf16v8*)&(base)[arowb + ((i0) + i_) * 1024 + (ck)];
#define RD_B(dst, ck, base)                                                              \
  _Pragma("unroll")                                                                      \
  for (int j_ = 0; j_ < 4; ++j_)                                                         \
    dst[j_] = *(const bf16v8*)&(base)[browb + j_ * 1024 + (ck)];
// 16 MFMA: one C-quadrant (4 A-rows x 4 B-cols)
#define MFMA_Q(i0, aarr, barr)                                                           \
  _Pragma("unroll")                                                                      \
  for (int i_ = 0; i_ < 4; ++i_) {                                                       \
    _Pragma("unroll")                                                                    \
    for (int j_ = 0; j_ < 4; ++j_)                                                       \
      acc[(i0) + i_][j_] = __builtin_amdgcn_mfma_f32_16x16x32_bf16(                      \
          aarr[i_], barr[j_], acc[(i0) + i_][j_], 0, 0, 0);                              \
  }
#define BAR __builtin_amdgcn_s_barrier()

// One K-tile = 4 phases. Reads for phase p issued in phase p-1 (registers aL/aH/bb0/bb1
// rotate with >=1-barrier WAR gaps). Stages: A(t+1) in ph1/ph2 (opposite parity buffer),
// B(t+2) in ph3/ph4 (same parity). vmcnt(2) at ph3-end retires A(t+1)+B(t+1) before the
// ph4 next-tile reads.
#define TILE_BODY(KT, CURB, NXTB)                                                        \
  do {                                                                                   \
    const unsigned short* Al = As + (CURB);                                              \
    const unsigned short* Bl = Bs + (CURB);                                              \
    /* ---- phase 1: MFMA aL(ks0)*bb0 ; issue aH-ks0 ; stage A(t+1)h0 */                 \
    RD_A(aH, 4, ck0, Al);                                                                \
    if ((KT) + 1 < NT) stageA((KT) + 1, 0, (NXTB));                                      \
    BAR;                                                                                 \
    __builtin_amdgcn_s_setprio(1);                                                       \
    MFMA_Q(0, aL, bb0);                                                                  \
    __builtin_amdgcn_s_setprio(0);                                                       \
    BAR;                                                                                 \
    /* ---- phase 2: MFMA aH(ks0)*bb0 ; issue bb1-ks1 + aL-ks1 ; stage A(t+1)h1 */       \
    RD_B(bb1, ck1, Bl);                                                                  \
    RD_A(aL, 0, ck1, Al);                                                                \
    if ((KT) + 1 < NT) stageA((KT) + 1, 1, (NXTB));                                      \
    BAR;                                                                                 \
    __builtin_amdgcn_s_setprio(1);                                                       \
    MFMA_Q(4, aH, bb0);                                                                  \
    __builtin_amdgcn_s_setprio(0);                                                       \
    asm volatile("s_waitcnt lgkmcnt(0)" ::: "memory");                                   \
    BAR;                                                                                 \
    /* ---- phase 3: MFMA aL(ks1)*bb1 ; issue aH-ks1 ; stage B(t+2)h0 ; vmcnt */         \
    RD_A(aH, 4, ck1, Al);                                                                \
    if ((KT) + 2 < NT) stageB((KT) + 2, 0, (CURB));                                      \
    BAR;                                                                                 \
    __builtin_amdgcn_s_setprio(1);                                                       \
    MFMA_Q(0, aL, bb1);                                                                  \
    __builtin_amdgcn_s_setprio(0);                                                       \
    if ((KT) < NT - 2) { asm volatile("s_waitcnt vmcnt(2)" ::: "memory"); }               \
    else               { asm volatile("s_waitcnt vmcnt(0)" ::: "memory"); }               \
    BAR;                                                                                 \
    /* ---- phase 4: MFMA aH(ks1)*bb1 ; issue next-tile aL-ks0 + bb0-ks0 ; stage B h1 */ \
    if ((KT) + 1 < NT) {                                                                 \
      RD_A(aL, 0, ck0, As + (NXTB));                                                     \
      RD_B(bb0, ck0, Bs + (NXTB));                                                       \
    }                                                                                    \
    if ((KT) + 2 < NT) stageB((KT) + 2, 1, (CURB));                                      \
    BAR;                                                                                 \
    __builtin_amdgcn_s_setprio(1);                                                       \
    MFMA_Q(4, aH, bb1);                                                                  \
    __builtin_amdgcn_s_setprio(0);                                                       \
    BAR;                                                                                 \
  } while (0)

// ---------------- 256x256 pipelined bf16 GEMM, C = A * B^T (both operands K-contiguous) ----
// MODE 0: QKV projection epilogue (Q / K / V-transposed)   MODE 1: bf16 store   MODE 2: f32 store
template <int MODE>
__global__ __launch_bounds__(512, 2) void gemm256(
    const unsigned short* __restrict__ A, const unsigned short* __restrict__ Bm,
    unsigned short* __restrict__ Cq, unsigned short* __restrict__ Ck,
    unsigned short* __restrict__ Cv, float* __restrict__ Cf,
    int K, int lda, int ldb,
    long aStride, long bStride, long cStride) {
  extern __shared__ unsigned short smem[];      // 65536 elems = 131072 B
  unsigned short* As = smem;                    // [2 buf][256 rows][64]
  unsigned short* Bs = smem + 32768;

  const int t = threadIdx.x;
  int bx = blockIdx.x, by = blockIdx.y, bz = blockIdx.z;
  {  // bijective XCD swizzle (all grids are %8==0)
    const int gx = gridDim.x, gy = gridDim.y;
    const int nwg = gx * gy * (int)gridDim.z;
    int id = bx + gx * (by + gy * bz);
    int sw = (id & 7) * (nwg >> 3) + (id >> 3);
    bx = sw % gx; int r2 = sw / gx;
    by = r2 % gy; bz = r2 / gy;
  }
  const int n0 = bx * 256, m0 = by * 256;
  const unsigned short* Ab = A + (size_t)bz * aStride;
  const unsigned short* Bb = Bm + (size_t)bz * bStride;

  const int lane = t & 63;
  const int w = t >> 6;
  const int wm = w >> 2, wn = w & 3;          // 2 x 4 wave grid; per-wave out 128x64
  const int frow = lane & 15;
  const int arowb = (wm * 128 + frow) * 64;   // + i*1024
  const int browb = (wn * 64 + frow) * 64;    // + j*1024
  // swizzled column-group offsets (elements) for kslice 0/1
  const int ck0 = (((lane >> 4) ^ (frow & 7)) * 8);
  const int ck1 = ((4 + (lane >> 4)) ^ (frow & 7)) * 8;

  // staging: 2 gload_lds per half-tile (128 rows x 64 cols); pre-swizzled global col
  const int srow = t >> 3;                          // 0..63
  const int gcol = ((t & 7) ^ (srow & 7)) * 8;      // source swizzle (involution)
  const int ldsw = (t >> 6) << 9;                   // wave-uniform LDS base (elems)
  const unsigned short* Asrc = Ab + (size_t)(m0 + srow) * lda + gcol;
  const unsigned short* Bsrc = Bb + (size_t)(n0 + srow) * ldb + gcol;

  auto stageA = [&](int tk, int h, int bufoff) {
    const unsigned short* s = Asrc + (size_t)(h * 128) * lda + tk * 64;
    unsigned short* d = &As[bufoff + (h << 13) + ldsw];
    gload_lds16(s, d);
    gload_lds16(s + (size_t)64 * lda, d + 4096);
  };
  auto stageB = [&](int tk, int h, int bufoff) {
    const unsigned short* s = Bsrc + (size_t)(h * 128) * ldb + tk * 64;
    unsigned short* d = &Bs[bufoff + (h << 13) + ldsw];
    gload_lds16(s, d);
    gload_lds16(s + (size_t)64 * ldb, d + 4096);
  };

  f32x4 acc[8][4] = {};
  const int NT = K >> 6;
  bf16v8 aL[4], aH[4], bb0[4], bb1[4];

  // prologue: tile0 A+B, tile1 B; retain tile1's B (4 gloads) in flight
  stageA(0, 0, 0); stageA(0, 1, 0);
  stageB(0, 0, 0); stageB(0, 1, 0);
  stageB(1, 0, 16384); stageB(1, 1, 16384);
  asm volatile("s_waitcnt vmcnt(4)" ::: "memory");
  BAR;
  RD_A(aL, 0, ck0, As);
  RD_B(bb0, ck0, Bs);

  for (int ktp = 0; ktp < NT; ktp += 2) {
    TILE_BODY(ktp, 0, 16384);
    TILE_BODY(ktp + 1, 16384, 0);
  }

  // Epilogue. C/D layout: col = lane&15, row = (lane>>4)*4 + reg  [HW-verified]
  const int r0 = (lane >> 4) * 4;
  const int c0 = lane & 15;
  const int mrowB = m0 + wm * 128 + r0;   // + i*16 + r
  const int ncolB = n0 + wn * 64 + c0;    // + j*16

  if (MODE == 0) {
    if (n0 < 1536) {  // Q or K region (block-uniform: 256 | 768)
      unsigned short* dst = (n0 < 768) ? Cq : Ck;
      const int cb = (n0 < 768) ? 0 : 768;
#pragma unroll
      for (int i = 0; i < 8; ++i)
#pragma unroll
        for (int j = 0; j < 4; ++j)
#pragma unroll
          for (int r = 0; r < 4; ++r)
            dst[(size_t)(mrowB + i * 16 + r) * DD + (ncolB + j * 16 - cb)] = f2b(acc[i][j][r]);
    } else {  // V region: store transposed Vt[b][e][n]
#pragma unroll
      for (int i = 0; i < 8; ++i) {
        int row = mrowB + i * 16;          // global token index = b*2048 + n
        int bb = row >> 11, nn = row & 2047;
#pragma unroll
        for (int j = 0; j < 4; ++j) {
          int e = ncolB + j * 16 - 1536;
          ushort4v pk;
#pragma unroll
          for (int r = 0; r < 4; ++r) pk[r] = f2b(acc[i][j][r]);
          *(ushort4v*)&Cv[((size_t)(bb * DD + e)) * NN + nn] = pk;
        }
      }
    }
  } else if (MODE == 1) {
    unsigned short* dst = Cq + (size_t)bz * cStride;
#pragma unroll
    for (int i = 0; i < 8; ++i)
#pragma unroll
      for (int j = 0; j < 4; ++j)
#pragma unroll
        for (int r = 0; r < 4; ++r)
          dst[(size_t)(mrowB + i * 16 + r) * NN + (ncolB + j * 16)] = f2b(acc[i][j][r]);
  } else {
    float* dst = Cf + (size_t)bz * cStride;
#pragma unroll
    for (int i = 0; i < 8; ++i)
#pragma unroll
      for (int j = 0; j < 4; ++j)
#pragma unroll
        for (int r = 0; r < 4; ++r)
          dst[(size_t)(mrowB + i * 16 + r) * DD + (ncolB + j * 16)] = acc[i][j][r];
  }
}

// ---------------- masked softmax, in-place on bf16 S rows ----------------
__global__ __launch_bounds__(256) void softmax_mask(unsigned short* __restrict__ S,
                                                    const int* __restrict__ mask) {
  int row = blockIdx.x;            // 0..16383
  int bb = row >> 11;
  unsigned short* sr = S + (size_t)row * NN;
  const int* mr = mask + bb * NN;
  int t = threadIdx.x;

  ushort8v pk = *(const ushort8v*)&sr[t * 8];
  float v[8];
  int msk[8];
#pragma unroll
  for (int j = 0; j < 8; ++j) msk[j] = mr[t * 8 + j];
  float mx = -1e30f;
#pragma unroll
  for (int j = 0; j < 8; ++j) {
    v[j] = b2f(pk[j]);
    if (!msk[j]) mx = fmaxf(mx, v[j]);
  }
  for (int o = 32; o > 0; o >>= 1) mx = fmaxf(mx, __shfl_xor(mx, o));
  __shared__ float redm[4], reds[4];
  int w = t >> 6, lane = t & 63;
  if (lane == 0) redm[w] = mx;
  __syncthreads();
  mx = fmaxf(fmaxf(redm[0], redm[1]), fmaxf(redm[2], redm[3]));

  float e[8];
  float sum = 0.f;
#pragma unroll
  for (int j = 0; j < 8; ++j) {
    e[j] = msk[j] ? 0.f : __expf(v[j] - mx);
    sum += e[j];
  }
  for (int o = 32; o > 0; o >>= 1) sum += __shfl_xor(sum, o);
  if (lane == 0) reds[w] = sum;
  __syncthreads();
  sum = reds[0] + reds[1] + reds[2] + reds[3];
  float inv = 1.0f / sum;

  ushort8v op;
#pragma unroll
  for (int j = 0; j < 8; ++j) op[j] = f2b(e[j] * inv);
  *(ushort8v*)&sr[t * 8] = op;
}

extern "C" void kernel_launch(void* const* d_in, const int* in_sizes, int n_in,
                              void* d_out, int out_size, void* d_ws, size_t ws_size,
                              hipStream_t stream) {
  const float* features = (const float*)d_in[0];
  const int* mask       = (const int*)d_in[1];
  const float* Wq       = (const float*)d_in[2];
  const float* Wk       = (const float*)d_in[3];
  const float* Wv       = (const float*)d_in[4];
  const float* gamma    = (const float*)d_in[5];
  const float* beta     = (const float*)d_in[6];
  float* out = (float*)d_out;

  char* ws = (char*)d_ws;
  size_t off = 0;
  auto alloc = [&](size_t bytes) {
    char* p = ws + off;
    off += (bytes + 255) & ~(size_t)255;
    return p;
  };
  unsigned short* Wcat = (unsigned short*)alloc((size_t)2304 * DD * 2);
  unsigned short* Qb   = (unsigned short*)alloc((size_t)BB * NN * DD * 2);
  unsigned short* Kb   = (unsigned short*)alloc((size_t)BB * NN * DD * 2);
  unsigned short* Vt   = (unsigned short*)alloc((size_t)BB * NN * DD * 2);
  // S (67 MB) aliases the X buffer region: X is dead once GEMM0 completes.
  char* last = alloc((size_t)BB * NN * NN * 2);
  unsigned short* Sb = (unsigned short*)last;
  unsigned short* Xb = (unsigned short*)last;  // first 25 MB of the S region

  // allow 128 KiB dynamic LDS (idempotent host-side config; not a stream op)
  (void)hipFuncSetAttribute(reinterpret_cast<const void*>(&gemm256<0>),
                            hipFuncAttributeMaxDynamicSharedMemorySize, 131072);
  (void)hipFuncSetAttribute(reinterpret_cast<const void*>(&gemm256<1>),
                            hipFuncAttributeMaxDynamicSharedMemorySize, 131072);
  (void)hipFuncSetAttribute(reinterpret_cast<const void*>(&gemm256<2>),
                            hipFuncAttributeMaxDynamicSharedMemorySize, 131072);

  ln_kernel<<<BB * NN, 256, 0, stream>>>(features, gamma, beta, Xb);
  wconvert<<<(3 * DD * DD + 255) / 256, 256, 0, stream>>>(Wq, Wk, Wv, Wcat);

  // QKV projection: [16384,768] x [2304,768]^T
  gemm256<0><<<dim3(2304 / 256, (BB * NN) / 256, 1), 512, 131072, stream>>>(
      Xb, Wcat, Qb, Kb, Vt, nullptr, DD, DD, DD, 0, 0, 0);

  // Scores: per batch [2048,768] x [2048,768]^T -> S bf16
  gemm256<1><<<dim3(NN / 256, NN / 256, BB), 512, 131072, stream>>>(
      Qb, Kb, Sb, nullptr, nullptr, nullptr, DD, DD, DD,
      (long)NN * DD, (long)NN * DD, (long)NN * NN);

  softmax_mask<<<BB * NN, 256, 0, stream>>>(Sb, mask);

  // Context: per batch P[2048,2048] x Vt[768,2048]^T -> f32 out
  gemm256<2><<<dim3(DD / 256, NN / 256, BB), 512, 131072, stream>>>(
      Sb, Vt, nullptr, nullptr, nullptr, out, NN, NN, NN,
      (long)NN * NN, (long)DD * NN, (long)NN * DD);
}

// Round 4
// 486.986 us; speedup vs baseline: 1.2640x; 1.2640x over previous
//
#include <hip/hip_runtime.h>
#include <hip/hip_bf16.h>
#include <cstdint>

typedef __attribute__((ext_vector_type(8))) __bf16 bf16v8;
typedef __attribute__((ext_vector_type(4))) float f32x4;
typedef __attribute__((ext_vector_type(4))) unsigned short ushort4v;
typedef __attribute__((ext_vector_type(8))) unsigned short ushort8v;

#define BB 8
#define NN 2048
#define DD 768

__device__ __forceinline__ float b2f(unsigned short u) {
  union { unsigned int i; float f; } c; c.i = ((unsigned int)u) << 16; return c.f;
}
__device__ __forceinline__ unsigned short f2b(float f) {
  union { float f; unsigned int i; } c; c.f = f;
  unsigned int u = c.i;
  return (unsigned short)((u + 0x7fffu + ((u >> 16) & 1u)) >> 16);
}

// ---------------- LayerNorm: f32 [16384][768] -> bf16 ----------------
__global__ __launch_bounds__(256) void ln_kernel(const float* __restrict__ x,
                                                 const float* __restrict__ gamma,
                                                 const float* __restrict__ beta,
                                                 unsigned short* __restrict__ xb) {
  int row = blockIdx.x;
  const float* xr = x + (size_t)row * DD;
  int t = threadIdx.x;
  float a0 = xr[t], a1 = xr[t + 256], a2 = xr[t + 512];
  float s = a0 + a1 + a2;
  float q = a0 * a0 + a1 * a1 + a2 * a2;
  for (int o = 32; o > 0; o >>= 1) { s += __shfl_xor(s, o); q += __shfl_xor(q, o); }
  __shared__ float red[2][4];
  int w = t >> 6, lane = t & 63;
  if (lane == 0) { red[0][w] = s; red[1][w] = q; }
  __syncthreads();
  s = red[0][0] + red[0][1] + red[0][2] + red[0][3];
  q = red[1][0] + red[1][1] + red[1][2] + red[1][3];
  float mean = s * (1.0f / DD);
  float var = q * (1.0f / DD) - mean * mean;
  float inv = rsqrtf(var + 1e-5f);
  unsigned short* o0 = xb + (size_t)row * DD;
  o0[t]       = f2b((a0 - mean) * inv * gamma[t]       + beta[t]);
  o0[t + 256] = f2b((a1 - mean) * inv * gamma[t + 256] + beta[t + 256]);
  o0[t + 512] = f2b((a2 - mean) * inv * gamma[t + 512] + beta[t + 512]);
}

// ------------- Weight concat/convert: Wcat[2304][768] bf16, scale folded into Wq -------------
__global__ __launch_bounds__(256) void wconvert(const float* __restrict__ Wq,
                                                const float* __restrict__ Wk,
                                                const float* __restrict__ Wv,
                                                unsigned short* __restrict__ Wcat) {
  int i = blockIdx.x * 256 + threadIdx.x;
  const int dd = DD * DD;
  if (i >= 3 * dd) return;
  float v;
  if (i < dd)           v = Wq[i] * 0.03608439182435161f;   // 1/sqrt(768)
  else if (i < 2 * dd)  v = Wk[i - dd];
  else                  v = Wv[i - 2 * dd];
  Wcat[i] = f2b(v);
}

// ---------------- async global->LDS (16B per lane, wave-uniform LDS base) ----------------
__device__ __forceinline__ void gload_lds16(const void* g, void* l) {
  __builtin_amdgcn_global_load_lds(
      (const __attribute__((address_space(1))) void*)g,
      (__attribute__((address_space(3))) void*)(unsigned)(uintptr_t)l,
      16, 0, 0);
}

// 4 A-frags (rows i0..i0+3) from swizzled LDS
#define RD_A(dst, i0, ck, base)                                                          \
  _Pragma("unroll")                                                                      \
  for (int i_ = 0; i_ < 4; ++i_)                                                         \
    dst[i_] = *(const bf16v8*)&(base)[arowb + ((i0) + i_) * 1024 + (ck)];
#define RD_B(dst, ck, base)                                                              \
  _Pragma("unroll")                                                                      \
  for (int j_ = 0; j_ < 4; ++j_)                                                         \
    dst[j_] = *(const bf16v8*)&(base)[browb + j_ * 1024 + (ck)];
// 16 MFMA: one C-quadrant (4 A-rows x 4 B-cols)
#define MFMA_Q(i0, aarr, barr)                                                           \
  _Pragma("unroll")                                                                      \
  for (int i_ = 0; i_ < 4; ++i_) {                                                       \
    _Pragma("unroll")                                                                    \
    for (int j_ = 0; j_ < 4; ++j_)                                                       \
      acc[(i0) + i_][j_] = __builtin_amdgcn_mfma_f32_16x16x32_bf16(                      \
          aarr[i_], barr[j_], acc[(i0) + i_][j_], 0, 0, 0);                              \
  }
#define BAR   __builtin_amdgcn_s_barrier()
#define LGKM0 asm volatile("s_waitcnt lgkmcnt(0)" ::: "memory")
#define P1    __builtin_amdgcn_s_setprio(1)
#define P0    __builtin_amdgcn_s_setprio(0)

// One K-tile = 4 phases; reads per phase 8/8/8/0 ds_read_b128, short operand liveness.
// Staging ledger (safe by construction):
//  ph1 -> A1(t+1) into NXTB   (NXTB writable: tile t-1 reads done by prev ph3-lgkm)
//  ph2 -> B0(t+1) into NXTB
//  ph3 -> B1(t+1) into NXTB
//  ph4 -> A0(t+2) into CURB   (CURB writable: tile t reads done by ph3-lgkm + BAR)
//  vmcnt(2) at ph4 (outstanding=10) drains tile t+1 fully, leaves A0(t+2) in flight.
#define TILE_BODY(KT, CURB, NXTB)                                                        \
  do {                                                                                   \
    const unsigned short* Al = As + (CURB);                                              \
    const unsigned short* Bl = Bs + (CURB);                                              \
    /* ---- phase 1: MFMA quad0-ks0 */                                                   \
    RD_A(aA, 0, ck0, Al);                                                                \
    RD_B(b0, ck0, Bl);                                                                   \
    if ((KT) + 1 < NT) stageA((KT) + 1, 1, (NXTB));                                      \
    BAR; LGKM0; P1;                                                                      \
    MFMA_Q(0, aA, b0);                                                                   \
    P0; BAR;                                                                             \
    /* ---- phase 2: MFMA quad1-ks0 */                                                   \
    RD_A(aB, 4, ck0, Al);                                                                \
    RD_A(aA, 0, ck1, Al);                                                                \
    if ((KT) + 1 < NT) stageB((KT) + 1, 0, (NXTB));                                      \
    BAR; LGKM0; P1;                                                                      \
    MFMA_Q(4, aB, b0);                                                                   \
    P0; BAR;                                                                             \
    /* ---- phase 3: MFMA quad0-ks1 (aA re-read ks1 in ph2) */                           \
    RD_A(aB, 4, ck1, Al);                                                                \
    RD_B(b1, ck1, Bl);                                                                   \
    if ((KT) + 1 < NT) stageB((KT) + 1, 1, (NXTB));                                      \
    BAR; LGKM0; P1;                                                                      \
    MFMA_Q(0, aA, b1);                                                                   \
    P0; BAR;                                                                             \
    /* ---- phase 4: MFMA quad1-ks1; stage A0(t+2); counted vmcnt */                     \
    if ((KT) + 2 < NT) stageA((KT) + 2, 0, (CURB));                                      \
    BAR; P1;                                                                             \
    MFMA_Q(4, aB, b1);                                                                   \
    P0;                                                                                  \
    if ((KT) + 2 < NT) { asm volatile("s_waitcnt vmcnt(2)" ::: "memory"); }              \
    else               { asm volatile("s_waitcnt vmcnt(0)" ::: "memory"); }              \
    BAR;                                                                                 \
  } while (0)

// ---------------- 256x256 pipelined bf16 GEMM, C = A * B^T (both operands K-contiguous) ----
// MODE 0: QKV projection epilogue (Q / K / V-transposed)   MODE 1: bf16 store   MODE 2: f32 store
template <int MODE>
__global__ __launch_bounds__(512, 2) void gemm256(
    const unsigned short* __restrict__ A, const unsigned short* __restrict__ Bm,
    unsigned short* __restrict__ Cq, unsigned short* __restrict__ Ck,
    unsigned short* __restrict__ Cv, float* __restrict__ Cf,
    int K, int lda, int ldb,
    long aStride, long bStride, long cStride) {
  extern __shared__ unsigned short smem[];      // 65536 elems = 131072 B
  unsigned short* As = smem;                    // [2 buf][2 half][128 rows][64]
  unsigned short* Bs = smem + 32768;

  const int t = threadIdx.x;
  int bx = blockIdx.x, by = blockIdx.y, bz = blockIdx.z;
  {  // bijective XCD swizzle (all grids are %8==0)
    const int gx = gridDim.x, gy = gridDim.y;
    const int nwg = gx * gy * (int)gridDim.z;
    int id = bx + gx * (by + gy * bz);
    int sw = (id & 7) * (nwg >> 3) + (id >> 3);
    bx = sw % gx; int r2 = sw / gx;
    by = r2 % gy; bz = r2 / gy;
  }
  const int n0 = bx * 256, m0 = by * 256;
  const unsigned short* Ab = A + (size_t)bz * aStride;
  const unsigned short* Bb = Bm + (size_t)bz * bStride;

  const int lane = t & 63;
  const int w = t >> 6;
  const int wm = w >> 2, wn = w & 3;          // 2 x 4 wave grid; per-wave out 128x64
  const int frow = lane & 15;
  const int arowb = (wm * 128 + frow) * 64;   // + i*1024
  const int browb = (wn * 64 + frow) * 64;    // + j*1024
  // swizzled column-group offsets (elements) for kslice 0/1
  const int ck0 = (((lane >> 4) ^ (frow & 7)) * 8);
  const int ck1 = ((4 + (lane >> 4)) ^ (frow & 7)) * 8;

  // staging: 2 gload_lds per half-tile (128 rows x 64 cols); pre-swizzled global col
  const int srow = t >> 3;                          // 0..63
  const int gcol = ((t & 7) ^ (srow & 7)) * 8;      // source swizzle (involution)
  const int ldsw = (t >> 6) << 9;                   // wave-uniform LDS base (elems)
  const unsigned short* Asrc = Ab + (size_t)(m0 + srow) * lda + gcol;
  const unsigned short* Bsrc = Bb + (size_t)(n0 + srow) * ldb + gcol;

  auto stageA = [&](int tk, int h, int bufoff) {
    const unsigned short* s = Asrc + (size_t)(h * 128) * lda + tk * 64;
    unsigned short* d = &As[bufoff + (h << 13) + ldsw];
    gload_lds16(s, d);
    gload_lds16(s + (size_t)64 * lda, d + 4096);
  };
  auto stageB = [&](int tk, int h, int bufoff) {
    const unsigned short* s = Bsrc + (size_t)(h * 128) * ldb + tk * 64;
    unsigned short* d = &Bs[bufoff + (h << 13) + ldsw];
    gload_lds16(s, d);
    gload_lds16(s + (size_t)64 * ldb, d + 4096);
  };

  f32x4 acc[8][4] = {};
  const int NT = K >> 6;
  bf16v8 aA[4], aB[4], b0[4], b1[4];

  // prologue: tile0 fully + A0(1); vmcnt(2) drains tile0, leaves A0(1) in flight
  stageA(0, 0, 0); stageA(0, 1, 0);
  stageB(0, 0, 0); stageB(0, 1, 0);
  stageA(1, 0, 16384);
  asm volatile("s_waitcnt vmcnt(2)" ::: "memory");
  BAR;

  for (int ktp = 0; ktp < NT; ktp += 2) {
    TILE_BODY(ktp, 0, 16384);
    TILE_BODY(ktp + 1, 16384, 0);
  }

  // Epilogue. C/D layout: col = lane&15, row = (lane>>4)*4 + reg  [HW-verified]
  const int r0 = (lane >> 4) * 4;
  const int c0 = lane & 15;
  const int mrowB = m0 + wm * 128 + r0;   // + i*16 + r
  const int ncolB = n0 + wn * 64 + c0;    // + j*16

  if (MODE == 0) {
    if (n0 < 1536) {  // Q or K region (block-uniform: 256 | 768)
      unsigned short* dst = (n0 < 768) ? Cq : Ck;
      const int cb = (n0 < 768) ? 0 : 768;
#pragma unroll
      for (int i = 0; i < 8; ++i)
#pragma unroll
        for (int j = 0; j < 4; ++j)
#pragma unroll
          for (int r = 0; r < 4; ++r)
            dst[(size_t)(mrowB + i * 16 + r) * DD + (ncolB + j * 16 - cb)] = f2b(acc[i][j][r]);
    } else {  // V region: store transposed Vt[b][e][n]
#pragma unroll
      for (int i = 0; i < 8; ++i) {
        int row = mrowB + i * 16;          // global token index = b*2048 + n
        int bb = row >> 11, nn = row & 2047;
#pragma unroll
        for (int j = 0; j < 4; ++j) {
          int e = ncolB + j * 16 - 1536;
          ushort4v pk;
#pragma unroll
          for (int r = 0; r < 4; ++r) pk[r] = f2b(acc[i][j][r]);
          *(ushort4v*)&Cv[((size_t)(bb * DD + e)) * NN + nn] = pk;
        }
      }
    }
  } else if (MODE == 1) {
    unsigned short* dst = Cq + (size_t)bz * cStride;
#pragma unroll
    for (int i = 0; i < 8; ++i)
#pragma unroll
      for (int j = 0; j < 4; ++j)
#pragma unroll
        for (int r = 0; r < 4; ++r)
          dst[(size_t)(mrowB + i * 16 + r) * NN + (ncolB + j * 16)] = f2b(acc[i][j][r]);
  } else {
    float* dst = Cf + (size_t)bz * cStride;
#pragma unroll
    for (int i = 0; i < 8; ++i)
#pragma unroll
      for (int j = 0; j < 4; ++j)
#pragma unroll
        for (int r = 0; r < 4; ++r)
          dst[(size_t)(mrowB + i * 16 + r) * DD + (ncolB + j * 16)] = acc[i][j][r];
  }
}

// ---------------- masked softmax, in-place on bf16 S rows ----------------
__global__ __launch_bounds__(256) void softmax_mask(unsigned short* __restrict__ S,
                                                    const int* __restrict__ mask) {
  int row = blockIdx.x;            // 0..16383
  int bb = row >> 11;
  unsigned short* sr = S + (size_t)row * NN;
  const int* mr = mask + bb * NN;
  int t = threadIdx.x;

  ushort8v pk = *(const ushort8v*)&sr[t * 8];
  float v[8];
  int msk[8];
#pragma unroll
  for (int j = 0; j < 8; ++j) msk[j] = mr[t * 8 + j];
  float mx = -1e30f;
#pragma unroll
  for (int j = 0; j < 8; ++j) {
    v[j] = b2f(pk[j]);
    if (!msk[j]) mx = fmaxf(mx, v[j]);
  }
  for (int o = 32; o > 0; o >>= 1) mx = fmaxf(mx, __shfl_xor(mx, o));
  __shared__ float redm[4], reds[4];
  int w = t >> 6, lane = t & 63;
  if (lane == 0) redm[w] = mx;
  __syncthreads();
  mx = fmaxf(fmaxf(redm[0], redm[1]), fmaxf(redm[2], redm[3]));

  float e[8];
  float sum = 0.f;
#pragma unroll
  for (int j = 0; j < 8; ++j) {
    e[j] = msk[j] ? 0.f : __expf(v[j] - mx);
    sum += e[j];
  }
  for (int o = 32; o > 0; o >>= 1) sum += __shfl_xor(sum, o);
  if (lane == 0) reds[w] = sum;
  __syncthreads();
  sum = reds[0] + reds[1] + reds[2] + reds[3];
  float inv = 1.0f / sum;

  ushort8v op;
#pragma unroll
  for (int j = 0; j < 8; ++j) op[j] = f2b(e[j] * inv);
  *(ushort8v*)&sr[t * 8] = op;
}

extern "C" void kernel_launch(void* const* d_in, const int* in_sizes, int n_in,
                              void* d_out, int out_size, void* d_ws, size_t ws_size,
                              hipStream_t stream) {
  const float* features = (const float*)d_in[0];
  const int* mask       = (const int*)d_in[1];
  const float* Wq       = (const float*)d_in[2];
  const float* Wk       = (const float*)d_in[3];
  const float* Wv       = (const float*)d_in[4];
  const float* gamma    = (const float*)d_in[5];
  const float* beta     = (const float*)d_in[6];
  float* out = (float*)d_out;

  char* ws = (char*)d_ws;
  size_t off = 0;
  auto alloc = [&](size_t bytes) {
    char* p = ws + off;
    off += (bytes + 255) & ~(size_t)255;
    return p;
  };
  unsigned short* Wcat = (unsigned short*)alloc((size_t)2304 * DD * 2);
  unsigned short* Qb   = (unsigned short*)alloc((size_t)BB * NN * DD * 2);
  unsigned short* Kb   = (unsigned short*)alloc((size_t)BB * NN * DD * 2);
  unsigned short* Vt   = (unsigned short*)alloc((size_t)BB * NN * DD * 2);
  // S (67 MB) aliases the X buffer region: X is dead once GEMM0 completes.
  char* last = alloc((size_t)BB * NN * NN * 2);
  unsigned short* Sb = (unsigned short*)last;
  unsigned short* Xb = (unsigned short*)last;  // first 25 MB of the S region

  // allow 128 KiB dynamic LDS (idempotent host-side config; not a stream op)
  (void)hipFuncSetAttribute(reinterpret_cast<const void*>(&gemm256<0>),
                            hipFuncAttributeMaxDynamicSharedMemorySize, 131072);
  (void)hipFuncSetAttribute(reinterpret_cast<const void*>(&gemm256<1>),
                            hipFuncAttributeMaxDynamicSharedMemorySize, 131072);
  (void)hipFuncSetAttribute(reinterpret_cast<const void*>(&gemm256<2>),
                            hipFuncAttributeMaxDynamicSharedMemorySize, 131072);

  ln_kernel<<<BB * NN, 256, 0, stream>>>(features, gamma, beta, Xb);
  wconvert<<<(3 * DD * DD + 255) / 256, 256, 0, stream>>>(Wq, Wk, Wv, Wcat);

  // QKV projection: [16384,768] x [2304,768]^T
  gemm256<0><<<dim3(2304 / 256, (BB * NN) / 256, 1), 512, 131072, stream>>>(
      Xb, Wcat, Qb, Kb, Vt, nullptr, DD, DD, DD, 0, 0, 0);

  // Scores: per batch [2048,768] x [2048,768]^T -> S bf16
  gemm256<1><<<dim3(NN / 256, NN / 256, BB), 512, 131072, stream>>>(
      Qb, Kb, Sb, nullptr, nullptr, nullptr, DD, DD, DD,
      (long)NN * DD, (long)NN * DD, (long)NN * NN);

  softmax_mask<<<BB * NN, 256, 0, stream>>>(Sb, mask);

  // Context: per batch P[2048,2048] x Vt[768,2048]^T -> f32 out
  gemm256<2><<<dim3(DD / 256, NN / 256, BB), 512, 131072, stream>>>(
      Sb, Vt, nullptr, nullptr, nullptr, out, NN, NN, NN,
      (long)NN * NN, (long)DD * NN, (long)NN * DD);
}

// Round 5
// 256.730 us; speedup vs baseline: 2.3977x; 1.8969x over previous
//
#include <hip/hip_runtime.h>
#include <hip/hip_bf16.h>
#include <cstdint>

typedef __attribute__((ext_vector_type(8))) __bf16 bf16v8;
typedef __attribute__((ext_vector_type(4))) float f32x4;
typedef __attribute__((ext_vector_type(4))) unsigned short ushort4v;
typedef __attribute__((ext_vector_type(8))) unsigned short ushort8v;

#define BB 8
#define NN 2048
#define DD 768

__device__ __forceinline__ float b2f(unsigned short u) {
  union { unsigned int i; float f; } c; c.i = ((unsigned int)u) << 16; return c.f;
}
__device__ __forceinline__ unsigned short f2b(float f) {
  union { float f; unsigned int i; } c; c.f = f;
  unsigned int u = c.i;
  return (unsigned short)((u + 0x7fffu + ((u >> 16) & 1u)) >> 16);
}

// ---------------- LayerNorm: f32 [16384][768] -> bf16 ----------------
__global__ __launch_bounds__(256) void ln_kernel(const float* __restrict__ x,
                                                 const float* __restrict__ gamma,
                                                 const float* __restrict__ beta,
                                                 unsigned short* __restrict__ xb) {
  int row = blockIdx.x;
  const float* xr = x + (size_t)row * DD;
  int t = threadIdx.x;
  float a0 = xr[t], a1 = xr[t + 256], a2 = xr[t + 512];
  float s = a0 + a1 + a2;
  float q = a0 * a0 + a1 * a1 + a2 * a2;
  for (int o = 32; o > 0; o >>= 1) { s += __shfl_xor(s, o); q += __shfl_xor(q, o); }
  __shared__ float red[2][4];
  int w = t >> 6, lane = t & 63;
  if (lane == 0) { red[0][w] = s; red[1][w] = q; }
  __syncthreads();
  s = red[0][0] + red[0][1] + red[0][2] + red[0][3];
  q = red[1][0] + red[1][1] + red[1][2] + red[1][3];
  float mean = s * (1.0f / DD);
  float var = q * (1.0f / DD) - mean * mean;
  float inv = rsqrtf(var + 1e-5f);
  unsigned short* o0 = xb + (size_t)row * DD;
  o0[t]       = f2b((a0 - mean) * inv * gamma[t]       + beta[t]);
  o0[t + 256] = f2b((a1 - mean) * inv * gamma[t + 256] + beta[t + 256]);
  o0[t + 512] = f2b((a2 - mean) * inv * gamma[t + 512] + beta[t + 512]);
}

// ------------- Weight concat/convert: Wcat[2304][768] bf16, scale folded into Wq -------------
__global__ __launch_bounds__(256) void wconvert(const float* __restrict__ Wq,
                                                const float* __restrict__ Wk,
                                                const float* __restrict__ Wv,
                                                unsigned short* __restrict__ Wcat) {
  int i = blockIdx.x * 256 + threadIdx.x;
  const int dd = DD * DD;
  if (i >= 3 * dd) return;
  float v;
  if (i < dd)           v = Wq[i] * 0.03608439182435161f;   // 1/sqrt(768)
  else if (i < 2 * dd)  v = Wk[i - dd];
  else                  v = Wv[i - 2 * dd];
  Wcat[i] = f2b(v);
}

// ---------------- async global->LDS (16B per lane, wave-uniform LDS base) ----------------
__device__ __forceinline__ void gload_lds16(const void* g, void* l) {
  __builtin_amdgcn_global_load_lds(
      (const __attribute__((address_space(1))) void*)g,
      (__attribute__((address_space(3))) void*)(unsigned)(uintptr_t)l,
      16, 0, 0);
}

// LDS geometry (elements): buffer b at b*32768.
//   slot A-ks at  buf + ks*8192          (256 rows x 32 cols, 64B rows)
//   slot B-ks at  buf + 16384 + ks*8192
// 64B rows -> ds_read_b128 start banks uniform (8 lanes / 16B slot) => conflict-optimal, no swizzle.
#define RDA(i0, ks, B)                                                                   \
  _Pragma("unroll")                                                                      \
  for (int i_ = 0; i_ < 4; ++i_)                                                         \
    aq[i_] = *(const bf16v8*)&smem[(B) + (ks) * 8192 + arow0 + ((i0) + i_) * 512 + kg8];
#define RDB(ks, B)                                                                       \
  _Pragma("unroll")                                                                      \
  for (int j_ = 0; j_ < 4; ++j_)                                                         \
    bq[j_] = *(const bf16v8*)&smem[(B) + 16384 + (ks) * 8192 + brow0 + j_ * 512 + kg8];
// 16 MFMA: one quad (4 A-rowblocks x 4 B-colblocks)
#define MFQ(i0)                                                                          \
  _Pragma("unroll")                                                                      \
  for (int i_ = 0; i_ < 4; ++i_) {                                                       \
    _Pragma("unroll")                                                                    \
    for (int j_ = 0; j_ < 4; ++j_)                                                       \
      acc[(i0) + i_][j_] = __builtin_amdgcn_mfma_f32_16x16x32_bf16(                      \
          aq[i_], bq[j_], acc[(i0) + i_][j_], 0, 0, 0);                                  \
  }
#define BARF asm volatile("s_barrier" ::: "memory")
#define VMC6 asm volatile("s_waitcnt vmcnt(6)" ::: "memory")
#define VMC0 asm volatile("s_waitcnt vmcnt(0)" ::: "memory")
#define P1   __builtin_amdgcn_s_setprio(1)
#define P0   __builtin_amdgcn_s_setprio(0)

// One K-tile = 4 balanced phases (reads 8/4/8/4 b128, 16 MFMA each, 1 half-tile staged each).
// Stage ledger (verified steady state + prologue + tails):
//   ph1: stage A-ks1(t+1) -> NXTB    ph2: stage B-ks1(t+1) -> NXTB
//   ph3: stage A-ks0(t+2) -> CURB    ph4: stage B-ks0(t+2) -> CURB
//   vmcnt(6) at even-phase ends (stage->consume distance >=5 phases); vmcnt(0) only at kt==NT-2.
// All reads consumed by same-phase MFMAs (compiler lgkm waits) -> WAR on slots closed by barrier.
#define TILEK(KT, CURB, NXTB)                                                            \
  do {                                                                                   \
    /* ---- phase 1: quad rows 0-3, ks0 */                                               \
    RDA(0, 0, CURB); RDB(0, CURB);                                                       \
    if ((KT) + 1 < NT) stgA((KT) + 1, 1, (NXTB));                                        \
    BARF; P1; MFQ(0); P0; BARF;                                                          \
    /* ---- phase 2: quad rows 4-7, ks0 (bq reused) */                                   \
    RDA(4, 0, CURB);                                                                     \
    if ((KT) + 1 < NT) stgB((KT) + 1, 1, (NXTB));                                        \
    BARF; P1; MFQ(4); P0;                                                                \
    VMC6; BARF;                                                                          \
    /* ---- phase 3: quad rows 0-3, ks1 */                                               \
    RDA(0, 1, CURB); RDB(1, CURB);                                                       \
    if ((KT) + 2 < NT) stgA((KT) + 2, 0, (CURB));                                        \
    BARF; P1; MFQ(0); P0; BARF;                                                          \
    /* ---- phase 4: quad rows 4-7, ks1 */                                               \
    RDA(4, 1, CURB);                                                                     \
    if ((KT) + 2 < NT) stgB((KT) + 2, 0, (CURB));                                        \
    BARF; P1; MFQ(4); P0;                                                                \
    if ((KT) < NT - 2) { VMC6; } else { VMC0; }                                          \
    BARF;                                                                                \
  } while (0)

// ---------------- 256x256 8-phase bf16 GEMM, C = A * B^T (both operands K-contiguous) ----
// MODE 0: QKV projection epilogue (Q / K / V-transposed)   MODE 1: bf16 store   MODE 2: f32 store
template <int MODE>
__global__ __launch_bounds__(512, 2) void gemm256(
    const unsigned short* __restrict__ A, const unsigned short* __restrict__ Bm,
    unsigned short* __restrict__ Cq, unsigned short* __restrict__ Ck,
    unsigned short* __restrict__ Cv, float* __restrict__ Cf,
    int K, int lda, int ldb,
    long aStride, long bStride, long cStride) {
  extern __shared__ unsigned short smem[];      // 65536 elems = 131072 B

  const int t = threadIdx.x;
  int bx = blockIdx.x, by = blockIdx.y, bz = blockIdx.z;
  {  // bijective XCD swizzle (all grids are %8==0)
    const int gx = gridDim.x, gy = gridDim.y;
    const int nwg = gx * gy * (int)gridDim.z;
    int id = bx + gx * (by + gy * bz);
    int sw = (id & 7) * (nwg >> 3) + (id >> 3);
    bx = sw % gx; int r2 = sw / gx;
    by = r2 % gy; bz = r2 / gy;
  }
  const int n0 = bx * 256, m0 = by * 256;
  const unsigned short* Ab = A + (size_t)bz * aStride;
  const unsigned short* Bb = Bm + (size_t)bz * bStride;

  const int lane = t & 63;
  const int w = t >> 6;
  const int wm = w >> 2, wn = w & 3;            // 2 x 4 wave grid; per-wave out 128x64
  const int frow = lane & 15;
  const int kg8 = (lane >> 4) * 8;
  const int arow0 = (wm * 128 + frow) * 32;     // + i*512 (rowblock)
  const int brow0 = (wn * 64 + frow) * 32;      // + j*512

  // staging: thread t covers slot row (t>>2)+128h, k-group (t&3); dest = wave-uniform + lane*16
  const unsigned short* Asrc = Ab + (size_t)(m0 + (t >> 2)) * lda + (t & 3) * 8;
  const unsigned short* Bsrc = Bb + (size_t)(n0 + (t >> 2)) * ldb + (t & 3) * 8;
  const int sdst = w * 512;

  auto stgA = [&](int kt, int ks, int bufb) {
    const unsigned short* s = Asrc + kt * 64 + ks * 32;
    gload_lds16(s, &smem[bufb + ks * 8192 + sdst]);
    gload_lds16(s + (size_t)128 * lda, &smem[bufb + ks * 8192 + 4096 + sdst]);
  };
  auto stgB = [&](int kt, int ks, int bufb) {
    const unsigned short* s = Bsrc + kt * 64 + ks * 32;
    gload_lds16(s, &smem[bufb + 16384 + ks * 8192 + sdst]);
    gload_lds16(s + (size_t)128 * ldb, &smem[bufb + 16384 + ks * 8192 + 4096 + sdst]);
  };

  f32x4 acc[8][4] = {};
  const int NT = K >> 6;
  bf16v8 aq[4], bq[4];

  // prologue: ks0(0), ks1(0), ks0(1) staged; vmcnt(8) retires ks0(0) (oldest 4 loads)
  stgA(0, 0, 0);     stgB(0, 0, 0);
  stgA(0, 1, 0);     stgB(0, 1, 0);
  stgA(1, 0, 32768); stgB(1, 0, 32768);
  asm volatile("s_waitcnt vmcnt(8)" ::: "memory");
  BARF;

  for (int ktp = 0; ktp < NT; ktp += 2) {
    TILEK(ktp, 0, 32768);
    TILEK(ktp + 1, 32768, 0);
  }

  // Epilogue. C/D layout: col = lane&15, row = (lane>>4)*4 + reg  [HW-verified]
  const int r0 = (lane >> 4) * 4;
  const int c0 = lane & 15;
  const int mrowB = m0 + wm * 128 + r0;   // + i*16 + r
  const int ncolB = n0 + wn * 64 + c0;    // + j*16

  if (MODE == 0) {
    if (n0 < 1536) {  // Q or K region (block-uniform: 256 | 768)
      unsigned short* dst = (n0 < 768) ? Cq : Ck;
      const int cb = (n0 < 768) ? 0 : 768;
#pragma unroll
      for (int i = 0; i < 8; ++i)
#pragma unroll
        for (int j = 0; j < 4; ++j)
#pragma unroll
          for (int r = 0; r < 4; ++r)
            dst[(size_t)(mrowB + i * 16 + r) * DD + (ncolB + j * 16 - cb)] = f2b(acc[i][j][r]);
    } else {  // V region: store transposed Vt[b][e][n]
#pragma unroll
      for (int i = 0; i < 8; ++i) {
        int row = mrowB + i * 16;          // global token index = b*2048 + n
        int bb = row >> 11, nn = row & 2047;
#pragma unroll
        for (int j = 0; j < 4; ++j) {
          int e = ncolB + j * 16 - 1536;
          ushort4v pk;
#pragma unroll
          for (int r = 0; r < 4; ++r) pk[r] = f2b(acc[i][j][r]);
          *(ushort4v*)&Cv[((size_t)(bb * DD + e)) * NN + nn] = pk;
        }
      }
    }
  } else if (MODE == 1) {
    unsigned short* dst = Cq + (size_t)bz * cStride;
#pragma unroll
    for (int i = 0; i < 8; ++i)
#pragma unroll
      for (int j = 0; j < 4; ++j)
#pragma unroll
        for (int r = 0; r < 4; ++r)
          dst[(size_t)(mrowB + i * 16 + r) * NN + (ncolB + j * 16)] = f2b(acc[i][j][r]);
  } else {
    float* dst = Cf + (size_t)bz * cStride;
#pragma unroll
    for (int i = 0; i < 8; ++i)
#pragma unroll
      for (int j = 0; j < 4; ++j)
#pragma unroll
        for (int r = 0; r < 4; ++r)
          dst[(size_t)(mrowB + i * 16 + r) * DD + (ncolB + j * 16)] = acc[i][j][r];
  }
}

// ---------------- masked softmax, in-place on bf16 S rows ----------------
__global__ __launch_bounds__(256) void softmax_mask(unsigned short* __restrict__ S,
                                                    const int* __restrict__ mask) {
  int row = blockIdx.x;            // 0..16383
  int bb = row >> 11;
  unsigned short* sr = S + (size_t)row * NN;
  const int* mr = mask + bb * NN;
  int t = threadIdx.x;

  ushort8v pk = *(const ushort8v*)&sr[t * 8];
  float v[8];
  int msk[8];
#pragma unroll
  for (int j = 0; j < 8; ++j) msk[j] = mr[t * 8 + j];
  float mx = -1e30f;
#pragma unroll
  for (int j = 0; j < 8; ++j) {
    v[j] = b2f(pk[j]);
    if (!msk[j]) mx = fmaxf(mx, v[j]);
  }
  for (int o = 32; o > 0; o >>= 1) mx = fmaxf(mx, __shfl_xor(mx, o));
  __shared__ float redm[4], reds[4];
  int w = t >> 6, lane = t & 63;
  if (lane == 0) redm[w] = mx;
  __syncthreads();
  mx = fmaxf(fmaxf(redm[0], redm[1]), fmaxf(redm[2], redm[3]));

  float e[8];
  float sum = 0.f;
#pragma unroll
  for (int j = 0; j < 8; ++j) {
    e[j] = msk[j] ? 0.f : __expf(v[j] - mx);
    sum += e[j];
  }
  for (int o = 32; o > 0; o >>= 1) sum += __shfl_xor(sum, o);
  if (lane == 0) reds[w] = sum;
  __syncthreads();
  sum = reds[0] + reds[1] + reds[2] + reds[3];
  float inv = 1.0f / sum;

  ushort8v op;
#pragma unroll
  for (int j = 0; j < 8; ++j) op[j] = f2b(e[j] * inv);
  *(ushort8v*)&sr[t * 8] = op;
}

extern "C" void kernel_launch(void* const* d_in, const int* in_sizes, int n_in,
                              void* d_out, int out_size, void* d_ws, size_t ws_size,
                              hipStream_t stream) {
  const float* features = (const float*)d_in[0];
  const int* mask       = (const int*)d_in[1];
  const float* Wq       = (const float*)d_in[2];
  const float* Wk       = (const float*)d_in[3];
  const float* Wv       = (const float*)d_in[4];
  const float* gamma    = (const float*)d_in[5];
  const float* beta     = (const float*)d_in[6];
  float* out = (float*)d_out;

  char* ws = (char*)d_ws;
  size_t off = 0;
  auto alloc = [&](size_t bytes) {
    char* p = ws + off;
    off += (bytes + 255) & ~(size_t)255;
    return p;
  };
  unsigned short* Wcat = (unsigned short*)alloc((size_t)2304 * DD * 2);
  unsigned short* Qb   = (unsigned short*)alloc((size_t)BB * NN * DD * 2);
  unsigned short* Kb   = (unsigned short*)alloc((size_t)BB * NN * DD * 2);
  unsigned short* Vt   = (unsigned short*)alloc((size_t)BB * NN * DD * 2);
  // S (67 MB) aliases the X buffer region: X is dead once GEMM0 completes.
  char* last = alloc((size_t)BB * NN * NN * 2);
  unsigned short* Sb = (unsigned short*)last;
  unsigned short* Xb = (unsigned short*)last;  // first 25 MB of the S region

  // allow 128 KiB dynamic LDS (idempotent host-side config; not a stream op)
  (void)hipFuncSetAttribute(reinterpret_cast<const void*>(&gemm256<0>),
                            hipFuncAttributeMaxDynamicSharedMemorySize, 131072);
  (void)hipFuncSetAttribute(reinterpret_cast<const void*>(&gemm256<1>),
                            hipFuncAttributeMaxDynamicSharedMemorySize, 131072);
  (void)hipFuncSetAttribute(reinterpret_cast<const void*>(&gemm256<2>),
                            hipFuncAttributeMaxDynamicSharedMemorySize, 131072);

  ln_kernel<<<BB * NN, 256, 0, stream>>>(features, gamma, beta, Xb);
  wconvert<<<(3 * DD * DD + 255) / 256, 256, 0, stream>>>(Wq, Wk, Wv, Wcat);

  // QKV projection: [16384,768] x [2304,768]^T
  gemm256<0><<<dim3(2304 / 256, (BB * NN) / 256, 1), 512, 131072, stream>>>(
      Xb, Wcat, Qb, Kb, Vt, nullptr, DD, DD, DD, 0, 0, 0);

  // Scores: per batch [2048,768] x [2048,768]^T -> S bf16
  gemm256<1><<<dim3(NN / 256, NN / 256, BB), 512, 131072, stream>>>(
      Qb, Kb, Sb, nullptr, nullptr, nullptr, DD, DD, DD,
      (long)NN * DD, (long)NN * DD, (long)NN * NN);

  softmax_mask<<<BB * NN, 256, 0, stream>>>(Sb, mask);

  // Context: per batch P[2048,2048] x Vt[768,2048]^T -> f32 out
  gemm256<2><<<dim3(DD / 256, NN / 256, BB), 512, 131072, stream>>>(
      Sb, Vt, nullptr, nullptr, nullptr, out, NN, NN, NN,
      (long)NN * NN, (long)DD * NN, (long)NN * DD);
}

// Round 6
// 241.499 us; speedup vs baseline: 2.5489x; 1.0631x over previous
//
#include <hip/hip_runtime.h>
#include <hip/hip_bf16.h>
#include <cstdint>

typedef __attribute__((ext_vector_type(8))) __bf16 bf16v8;
typedef __attribute__((ext_vector_type(4))) float f32x4;
typedef __attribute__((ext_vector_type(4))) unsigned short ushort4v;
typedef __attribute__((ext_vector_type(8))) unsigned short ushort8v;

#define BB 8
#define NN 2048
#define DD 768

__device__ __forceinline__ float b2f(unsigned short u) {
  union { unsigned int i; float f; } c; c.i = ((unsigned int)u) << 16; return c.f;
}
__device__ __forceinline__ unsigned short f2b(float f) {
  union { float f; unsigned int i; } c; c.f = f;
  unsigned int u = c.i;
  return (unsigned short)((u + 0x7fffu + ((u >> 16) & 1u)) >> 16);
}

// ---------------- LayerNorm: f32 [16384][768] -> bf16 ----------------
__global__ __launch_bounds__(256) void ln_kernel(const float* __restrict__ x,
                                                 const float* __restrict__ gamma,
                                                 const float* __restrict__ beta,
                                                 unsigned short* __restrict__ xb) {
  int row = blockIdx.x;
  const float* xr = x + (size_t)row * DD;
  int t = threadIdx.x;
  float a0 = xr[t], a1 = xr[t + 256], a2 = xr[t + 512];
  float s = a0 + a1 + a2;
  float q = a0 * a0 + a1 * a1 + a2 * a2;
  for (int o = 32; o > 0; o >>= 1) { s += __shfl_xor(s, o); q += __shfl_xor(q, o); }
  __shared__ float red[2][4];
  int w = t >> 6, lane = t & 63;
  if (lane == 0) { red[0][w] = s; red[1][w] = q; }
  __syncthreads();
  s = red[0][0] + red[0][1] + red[0][2] + red[0][3];
  q = red[1][0] + red[1][1] + red[1][2] + red[1][3];
  float mean = s * (1.0f / DD);
  float var = q * (1.0f / DD) - mean * mean;
  float inv = rsqrtf(var + 1e-5f);
  unsigned short* o0 = xb + (size_t)row * DD;
  o0[t]       = f2b((a0 - mean) * inv * gamma[t]       + beta[t]);
  o0[t + 256] = f2b((a1 - mean) * inv * gamma[t + 256] + beta[t + 256]);
  o0[t + 512] = f2b((a2 - mean) * inv * gamma[t + 512] + beta[t + 512]);
}

// ------------- Weight concat/convert: Wcat[2304][768] bf16, scale folded into Wq -------------
__global__ __launch_bounds__(256) void wconvert(const float* __restrict__ Wq,
                                                const float* __restrict__ Wk,
                                                const float* __restrict__ Wv,
                                                unsigned short* __restrict__ Wcat) {
  int i = blockIdx.x * 256 + threadIdx.x;
  const int dd = DD * DD;
  if (i >= 3 * dd) return;
  float v;
  if (i < dd)           v = Wq[i] * 0.03608439182435161f;   // 1/sqrt(768)
  else if (i < 2 * dd)  v = Wk[i - dd];
  else                  v = Wv[i - 2 * dd];
  Wcat[i] = f2b(v);
}

// ---------------- async global->LDS (16B per lane, wave-uniform LDS base) ----------------
__device__ __forceinline__ void gload_lds16(const void* g, void* l) {
  __builtin_amdgcn_global_load_lds(
      (const __attribute__((address_space(1))) void*)g,
      (__attribute__((address_space(3))) void*)(unsigned)(uintptr_t)l,
      16, 0, 0);
}

// LDS geometry (elements): buffer b at b*32768.
//   slot A-ks at  buf + ks*8192          (256 rows x 32 cols, 64B rows)
//   slot B-ks at  buf + 16384 + ks*8192  (B slot sized for 256 rows; only BN rows read)
#define RDA(i0, ks, B)                                                                   \
  _Pragma("unroll")                                                                      \
  for (int i_ = 0; i_ < 4; ++i_)                                                         \
    aq[i_] = *(const bf16v8*)&smem[(B) + (ks) * 8192 + arow0 + ((i0) + i_) * 512 + kg8];
#define RDB(ks, B)                                                                       \
  _Pragma("unroll")                                                                      \
  for (int j_ = 0; j_ < NJ; ++j_)                                                        \
    bq[j_] = *(const bf16v8*)&smem[(B) + 16384 + (ks) * 8192 + brow0 + j_ * 512 + kg8];
// NJ*4 MFMA: one quad-row group (4 A-rowblocks x NJ B-colblocks)
#define MFQ(i0)                                                                          \
  _Pragma("unroll")                                                                      \
  for (int i_ = 0; i_ < 4; ++i_) {                                                       \
    _Pragma("unroll")                                                                    \
    for (int j_ = 0; j_ < NJ; ++j_)                                                      \
      acc[(i0) + i_][j_] = __builtin_amdgcn_mfma_f32_16x16x32_bf16(                      \
          aq[i_], bq[j_], acc[(i0) + i_][j_], 0, 0, 0);                                  \
  }
#define BARF asm volatile("s_barrier" ::: "memory")
#define VMC6 asm volatile("s_waitcnt vmcnt(6)" ::: "memory")
#define VMC0 asm volatile("s_waitcnt vmcnt(0)" ::: "memory")
#define P1   __builtin_amdgcn_s_setprio(1)
#define P0   __builtin_amdgcn_s_setprio(0)

// One K-tile = 4 balanced phases. Stage ledger (verified per-wave, uniform 2 gloads/chunk):
//   ph1: stage A-ks1(t+1) -> NXTB    ph2: stage B-ks1(t+1) -> NXTB
//   ph3: stage A-ks0(t+2) -> CURB    ph4: stage B-ks0(t+2) -> CURB
//   VMC6 at ph2-end retires A-ks0(t+1); VMC6 at ph4-end retires B-ks0(t+1)+A-ks1(t+1);
//   B-ks1(t+1) retired by ph2(t+1)-end VMC6 before ph3(t+1) reads it. Tail: VMC0 at kt==NT-2.
#define TILEK(KT, CURB, NXTB)                                                            \
  do {                                                                                   \
    /* ---- phase 1: quad rows 0-3, ks0 */                                               \
    RDA(0, 0, CURB); RDB(0, CURB);                                                       \
    if ((KT) + 1 < NT) stgA((KT) + 1, 1, (NXTB));                                        \
    BARF; P1; MFQ(0); P0; BARF;                                                          \
    /* ---- phase 2: quad rows 4-7, ks0 (bq reused) */                                   \
    RDA(4, 0, CURB);                                                                     \
    if ((KT) + 1 < NT) stgB((KT) + 1, 1, (NXTB));                                        \
    BARF; P1; MFQ(4); P0;                                                                \
    VMC6; BARF;                                                                          \
    /* ---- phase 3: quad rows 0-3, ks1 */                                               \
    RDA(0, 1, CURB); RDB(1, CURB);                                                       \
    if ((KT) + 2 < NT) stgA((KT) + 2, 0, (CURB));                                        \
    BARF; P1; MFQ(0); P0; BARF;                                                          \
    /* ---- phase 4: quad rows 4-7, ks1 */                                               \
    RDA(4, 1, CURB);                                                                     \
    if ((KT) + 2 < NT) stgB((KT) + 2, 0, (CURB));                                        \
    BARF; P1; MFQ(4); P0;                                                                \
    if ((KT) < NT - 2) { VMC6; } else { VMC0; }                                          \
    BARF;                                                                                \
  } while (0)

// ---------------- 256xBN pipelined bf16 GEMM, C = A * B^T (both operands K-contiguous) ----
// BN = NJ*64 (NJ=4 -> 256-wide, NJ=3 -> 192-wide). 512 threads = 8 waves (2M x 4N);
// per-wave output 128 x NJ*16... (128 x 48/64). B LDS slot padded to 256 rows; B source
// over-reads rows BN..255 (workspace padded) which are staged but never consumed.
// MODE 0: QKV projection epilogue (Q / K / V-transposed)   MODE 1: bf16 store   MODE 2: f32 store
template <int MODE, int NJ>
__global__ __launch_bounds__(512, 2) void gemm256(
    const unsigned short* __restrict__ A, const unsigned short* __restrict__ Bm,
    unsigned short* __restrict__ Cq, unsigned short* __restrict__ Ck,
    unsigned short* __restrict__ Cv, float* __restrict__ Cf,
    int K, int lda, int ldb,
    long aStride, long bStride, long cStride) {
  extern __shared__ unsigned short smem[];      // 65536 elems = 131072 B
  const int BN = NJ * 64;

  const int t = threadIdx.x;
  int bx = blockIdx.x, by = blockIdx.y, bz = blockIdx.z;
  {  // bijective XCD swizzle (all grids are %8==0)
    const int gx = gridDim.x, gy = gridDim.y;
    const int nwg = gx * gy * (int)gridDim.z;
    int id = bx + gx * (by + gy * bz);
    int sw = (id & 7) * (nwg >> 3) + (id >> 3);
    bx = sw % gx; int r2 = sw / gx;
    by = r2 % gy; bz = r2 / gy;
  }
  const int n0 = bx * BN, m0 = by * 256;
  const unsigned short* Ab = A + (size_t)bz * aStride;
  const unsigned short* Bb = Bm + (size_t)bz * bStride;

  const int lane = t & 63;
  const int w = t >> 6;
  const int wm = w >> 2, wn = w & 3;            // 2 x 4 wave grid; per-wave out 128 x BN/4
  const int frow = lane & 15;
  const int kg8 = (lane >> 4) * 8;
  const int arow0 = (wm * 128 + frow) * 32;     // + i*512 (rowblock)
  const int brow0 = (wn * (NJ * 16) + frow) * 32;  // + j*512

  // staging: thread t covers slot row (t>>2)+128h, k-group (t&3); dest = wave-uniform + lane*16
  const unsigned short* Asrc = Ab + (size_t)(m0 + (t >> 2)) * lda + (t & 3) * 8;
  const unsigned short* Bsrc = Bb + (size_t)(n0 + (t >> 2)) * ldb + (t & 3) * 8;
  const int sdst = w * 512;

  auto stgA = [&](int kt, int ks, int bufb) {
    const unsigned short* s = Asrc + kt * 64 + ks * 32;
    gload_lds16(s, &smem[bufb + ks * 8192 + sdst]);
    gload_lds16(s + (size_t)128 * lda, &smem[bufb + ks * 8192 + 4096 + sdst]);
  };
  auto stgB = [&](int kt, int ks, int bufb) {
    const unsigned short* s = Bsrc + kt * 64 + ks * 32;
    gload_lds16(s, &smem[bufb + 16384 + ks * 8192 + sdst]);
    gload_lds16(s + (size_t)128 * ldb, &smem[bufb + 16384 + ks * 8192 + 4096 + sdst]);
  };

  f32x4 acc[8][NJ] = {};
  const int NT = K >> 6;
  bf16v8 aq[4], bq[NJ];

  // prologue: ks0(0), ks1(0), ks0(1) staged; vmcnt(8) retires ks0(0) (oldest 4 loads)
  stgA(0, 0, 0);     stgB(0, 0, 0);
  stgA(0, 1, 0);     stgB(0, 1, 0);
  stgA(1, 0, 32768); stgB(1, 0, 32768);
  asm volatile("s_waitcnt vmcnt(8)" ::: "memory");
  BARF;

  for (int ktp = 0; ktp < NT; ktp += 2) {
    TILEK(ktp, 0, 32768);
    TILEK(ktp + 1, 32768, 0);
  }

  // Epilogue. C/D layout: col = lane&15, row = (lane>>4)*4 + reg  [HW-verified]
  const int r0 = (lane >> 4) * 4;
  const int c0 = lane & 15;
  const int mrowB = m0 + wm * 128 + r0;          // + i*16 + r
  const int ncolB = n0 + wn * (NJ * 16) + c0;    // + j*16

  if (MODE == 0) {
    if (n0 < 1536) {  // Q or K region (block-uniform: BN | 768)
      unsigned short* dst = (n0 < 768) ? Cq : Ck;
      const int cb = (n0 < 768) ? 0 : 768;
#pragma unroll
      for (int i = 0; i < 8; ++i)
#pragma unroll
        for (int j = 0; j < NJ; ++j)
#pragma unroll
          for (int r = 0; r < 4; ++r)
            dst[(size_t)(mrowB + i * 16 + r) * DD + (ncolB + j * 16 - cb)] = f2b(acc[i][j][r]);
    } else {  // V region: store transposed Vt[b][e][n]
#pragma unroll
      for (int i = 0; i < 8; ++i) {
        int row = mrowB + i * 16;          // global token index = b*2048 + n
        int bb = row >> 11, nn = row & 2047;
#pragma unroll
        for (int j = 0; j < NJ; ++j) {
          int e = ncolB + j * 16 - 1536;
          ushort4v pk;
#pragma unroll
          for (int r = 0; r < 4; ++r) pk[r] = f2b(acc[i][j][r]);
          *(ushort4v*)&Cv[((size_t)(bb * DD + e)) * NN + nn] = pk;
        }
      }
    }
  } else if (MODE == 1) {
    unsigned short* dst = Cq + (size_t)bz * cStride;
#pragma unroll
    for (int i = 0; i < 8; ++i)
#pragma unroll
      for (int j = 0; j < NJ; ++j)
#pragma unroll
        for (int r = 0; r < 4; ++r)
          dst[(size_t)(mrowB + i * 16 + r) * NN + (ncolB + j * 16)] = f2b(acc[i][j][r]);
  } else {
    float* dst = Cf + (size_t)bz * cStride;
#pragma unroll
    for (int i = 0; i < 8; ++i)
#pragma unroll
      for (int j = 0; j < NJ; ++j)
#pragma unroll
        for (int r = 0; r < 4; ++r)
          dst[(size_t)(mrowB + i * 16 + r) * DD + (ncolB + j * 16)] = acc[i][j][r];
  }
}

// ---------------- masked softmax, in-place on bf16 S rows ----------------
__global__ __launch_bounds__(256) void softmax_mask(unsigned short* __restrict__ S,
                                                    const int* __restrict__ mask) {
  int row = blockIdx.x;            // 0..16383
  int bb = row >> 11;
  unsigned short* sr = S + (size_t)row * NN;
  const int* mr = mask + bb * NN;
  int t = threadIdx.x;

  ushort8v pk = *(const ushort8v*)&sr[t * 8];
  float v[8];
  int msk[8];
#pragma unroll
  for (int j = 0; j < 8; ++j) msk[j] = mr[t * 8 + j];
  float mx = -1e30f;
#pragma unroll
  for (int j = 0; j < 8; ++j) {
    v[j] = b2f(pk[j]);
    if (!msk[j]) mx = fmaxf(mx, v[j]);
  }
  for (int o = 32; o > 0; o >>= 1) mx = fmaxf(mx, __shfl_xor(mx, o));
  __shared__ float redm[4], reds[4];
  int w = t >> 6, lane = t & 63;
  if (lane == 0) redm[w] = mx;
  __syncthreads();
  mx = fmaxf(fmaxf(redm[0], redm[1]), fmaxf(redm[2], redm[3]));

  float e[8];
  float sum = 0.f;
#pragma unroll
  for (int j = 0; j < 8; ++j) {
    e[j] = msk[j] ? 0.f : __expf(v[j] - mx);
    sum += e[j];
  }
  for (int o = 32; o > 0; o >>= 1) sum += __shfl_xor(sum, o);
  if (lane == 0) reds[w] = sum;
  __syncthreads();
  sum = reds[0] + reds[1] + reds[2] + reds[3];
  float inv = 1.0f / sum;

  ushort8v op;
#pragma unroll
  for (int j = 0; j < 8; ++j) op[j] = f2b(e[j] * inv);
  *(ushort8v*)&sr[t * 8] = op;
}

extern "C" void kernel_launch(void* const* d_in, const int* in_sizes, int n_in,
                              void* d_out, int out_size, void* d_ws, size_t ws_size,
                              hipStream_t stream) {
  const float* features = (const float*)d_in[0];
  const int* mask       = (const int*)d_in[1];
  const float* Wq       = (const float*)d_in[2];
  const float* Wk       = (const float*)d_in[3];
  const float* Wv       = (const float*)d_in[4];
  const float* gamma    = (const float*)d_in[5];
  const float* beta     = (const float*)d_in[6];
  float* out = (float*)d_out;

  char* ws = (char*)d_ws;
  size_t off = 0;
  auto alloc = [&](size_t bytes) {
    char* p = ws + off;
    off += (bytes + 255) & ~(size_t)255;
    return p;
  };
  // Wcat padded by 64 rows (over-read by 192-wide B staging at the last N-tile)
  unsigned short* Wcat = (unsigned short*)alloc((size_t)(2304 + 64) * DD * 2);
  unsigned short* Qb   = (unsigned short*)alloc((size_t)BB * NN * DD * 2);
  unsigned short* Kb   = (unsigned short*)alloc((size_t)BB * NN * DD * 2);
  // Vt padded by 64 rows of 2048 (over-read at last e-tile of last batch)
  unsigned short* Vt   = (unsigned short*)alloc(((size_t)BB * DD + 64) * NN * 2);
  // S (67 MB) aliases the X buffer region: X is dead once GEMM0 completes.
  char* last = alloc((size_t)BB * NN * NN * 2);
  unsigned short* Sb = (unsigned short*)last;
  unsigned short* Xb = (unsigned short*)last;  // first 25 MB of the S region

  // allow 128 KiB dynamic LDS (idempotent host-side config; not a stream op)
  (void)hipFuncSetAttribute(reinterpret_cast<const void*>(&gemm256<0, 3>),
                            hipFuncAttributeMaxDynamicSharedMemorySize, 131072);
  (void)hipFuncSetAttribute(reinterpret_cast<const void*>(&gemm256<1, 4>),
                            hipFuncAttributeMaxDynamicSharedMemorySize, 131072);
  (void)hipFuncSetAttribute(reinterpret_cast<const void*>(&gemm256<2, 3>),
                            hipFuncAttributeMaxDynamicSharedMemorySize, 131072);

  ln_kernel<<<BB * NN, 256, 0, stream>>>(features, gamma, beta, Xb);
  wconvert<<<(3 * DD * DD + 255) / 256, 256, 0, stream>>>(Wq, Wk, Wv, Wcat);

  // QKV projection: [16384,768] x [2304,768]^T ; 12 x 64 = 768 blocks = 3.0/CU exact
  gemm256<0, 3><<<dim3(2304 / 192, (BB * NN) / 256, 1), 512, 131072, stream>>>(
      Xb, Wcat, Qb, Kb, Vt, nullptr, DD, DD, DD, 0, 0, 0);

  // Scores: per batch [2048,768] x [2048,768]^T -> S bf16 ; 8x8x8 = 512 = 2.0/CU exact
  gemm256<1, 4><<<dim3(NN / 256, NN / 256, BB), 512, 131072, stream>>>(
      Qb, Kb, Sb, nullptr, nullptr, nullptr, DD, DD, DD,
      (long)NN * DD, (long)NN * DD, (long)NN * NN);

  softmax_mask<<<BB * NN, 256, 0, stream>>>(Sb, mask);

  // Context: per batch P[2048,2048] x Vt[768,2048]^T -> f32 out ; 4x8x8 = 256 = 1.0/CU exact
  gemm256<2, 3><<<dim3(DD / 192, NN / 256, BB), 512, 131072, stream>>>(
      Sb, Vt, nullptr, nullptr, nullptr, out, NN, NN, NN,
      (long)NN * NN, (long)DD * NN, (long)NN * DD);
}